// Round 4
// baseline (415.953 us; speedup 1.0000x reference)
//
#include <hip/hip_runtime.h>
#include <math.h>

#define NB 32
#define NS 4096
#define ND 512
#define NU 128
#define RR 64          // rows of values per block

typedef __bf16 bf16x8 __attribute__((ext_vector_type(8)));
typedef unsigned short u16x8 __attribute__((ext_vector_type(8)));
typedef float f32x4 __attribute__((ext_vector_type(4)));

union FragCvt { u16x8 u; bf16x8 b; };

__device__ inline unsigned short f2bf(float x) {
  union { float f; unsigned u; } v; v.f = x;
  return (unsigned short)((v.u + 0x7FFFu + ((v.u >> 16) & 1u)) >> 16);
}
__device__ inline float bf2f(unsigned int bits16) {  // low 16 bits are bf16
  union { unsigned u; float f; } v; v.u = bits16 << 16;
  return v.f;
}
__device__ inline float fast_tanh(float x) {
  x = fminf(9.f, fmaxf(-9.f, x));
  float e2 = __expf(2.f * x);
  return (e2 - 1.f) * __builtin_amdgcn_rcpf(e2 + 1.f);
}
// B-tile XOR swizzle: spread 8 consecutive 128B-rows across 8 16B slots
__device__ inline int bswz(int byte) { return byte ^ (((byte >> 7) & 7) << 4); }
// A-tile XOR swizzle: row-dependent 16B-slot permutation within the 1KB row
__device__ inline int aswz(int row, int byte) { return row * 1024 + (byte ^ ((row & 7) << 4)); }

// ---------------- prep: qb[b][u] += partial(query@W1) + b1 + b2 (split-K, qb pre-zeroed) ----------------
__global__ void prep_qb(const float* __restrict__ q, const float* __restrict__ W1,
                        const float* __restrict__ b1, const float* __restrict__ b2,
                        float* __restrict__ qb) {
  const int bb = blockIdx.x >> 4;
  const int kc = blockIdx.x & 15;
  const int u  = threadIdx.x & 127;
  const int dh = threadIdx.x >> 7;
  const int d0 = kc * 32 + dh * 16;
  const float* qr = q + bb * ND + d0;
  const float* w  = W1 + (size_t)d0 * NU + u;
  float s = (kc == 0 && dh == 0) ? (b1[u] + b2[u]) : 0.f;
  #pragma unroll
  for (int j = 0; j < 16; ++j) s += qr[j] * w[j * NU];
  atomicAdd(qb + bb * NU + u, s);
}

// ---------------- prep: W2 -> k-tile-major bf16: w2s[kt][u][k'] ----------------
__global__ void prep_w2s(const float* __restrict__ W2, unsigned short* __restrict__ w2s) {
  const int idx = blockIdx.x * 256 + threadIdx.x;   // 65536
  const int u = idx & 127;
  const int r = idx >> 7;
  const int k = r & 31, kt = r >> 5;
  w2s[kt * 4096 + u * 32 + k] = f2bf(W2[(size_t)(kt * 32 + k) * NU + u]);
}

// ---------------- fused: proj -> tanh -> score -> exp -> partial softmax + context ----------------
// RR=64: B (full 128KB w2s re-read per block) amortized over 2x rows -> 16.4K lines/CU vs 24.6K.
// LDS = 64KB A (XOR-swizzled, no pad) + 16KB B dbuf = 81920 B exactly -> 2 blocks/CU.
// Epilogue score/exp buffers overlay the dead B region (union).
__global__ __launch_bounds__(256, 2) void fused_attn(
    const float* __restrict__ values,
    const float* __restrict__ qb,            // [NB][NU]
    const unsigned short* __restrict__ w2s,  // [16][128][32] bf16 bits
    const float* __restrict__ V,             // [NU]
    const float* __restrict__ bvp,           // [1]
    float* __restrict__ wout,                // [NB][NS] unnormalized e^s
    float* __restrict__ Cacc,                // [NB][ND] partial context (ws, zeroed)
    float* __restrict__ Lacc)                // [NB] partial denom (ws, zeroed)
{
  __shared__ unsigned short Alds[RR * 512];      // 65,536 B (swizzled rows of 1024 B)
  __shared__ union {
    unsigned short B[2][4096];                   // 16,384 B dbuf
    struct { float sw[64]; float e[64]; } t;     // overlays B[0][0..256) - dead by then
  } Bsh;

  const int tid = threadIdx.x;
  const int b = blockIdx.x >> 6;        // 64 chunks per batch
  const int chunk = blockIdx.x & 63;
  const int s0 = chunk * RR;

  // ---- issue B[kt=0] prefetch first (L2-resident w2s) ----
  const uint4* w2s4 = (const uint4*)w2s;    // one kt tile = 512 uint4
  uint4 breg0 = w2s4[tid * 2];
  uint4 breg1 = w2s4[tid * 2 + 1];

  // ---- stage A: values[b][s0..s0+63][:] fp32 -> bf16 LDS (swizzled); 8 loads in flight ----
  const float* vbase = values + ((size_t)b * NS + s0) * ND;
  char* Ab = (char*)Alds;
  #pragma unroll
  for (int ii = 0; ii < 32; ii += 8) {
    float4 v[8];
    #pragma unroll
    for (int j = 0; j < 8; ++j) {
      const int f = tid + 256 * (ii + j);            // float4 index in [0, 8192)
      v[j] = *(const float4*)(vbase + (f >> 7) * ND + (f & 127) * 4);
    }
    #pragma unroll
    for (int j = 0; j < 8; ++j) {
      const int f = tid + 256 * (ii + j);
      const int row = f >> 7, c4 = f & 127;
      ushort4 pk;
      pk.x = f2bf(v[j].x); pk.y = f2bf(v[j].y); pk.z = f2bf(v[j].z); pk.w = f2bf(v[j].w);
      *(ushort4*)(Ab + aswz(row, c4 * 8)) = pk;
    }
  }

  const int wave = tid >> 6, lane = tid & 63;
  const int quad = lane >> 4, lidx = lane & 15;
  // wave owns rows wave*16 .. +15, all 128 u-columns

  f32x4 acc[8] = {{0.f,0.f,0.f,0.f},{0.f,0.f,0.f,0.f},{0.f,0.f,0.f,0.f},{0.f,0.f,0.f,0.f},
                  {0.f,0.f,0.f,0.f},{0.f,0.f,0.f,0.f},{0.f,0.f,0.f,0.f},{0.f,0.f,0.f,0.f}};
  const int arow = wave * 16 + lidx;
  const int arswz = (arow & 7) << 4;
  const char* Arow = Ab + arow * 1024;

  for (int kt = 0; kt < 16; ++kt) {
    char* bdst = (char*)Bsh.B[kt & 1];
    const int by0 = tid * 32;
    *(uint4*)(bdst + bswz(by0))      = breg0;   // vmcnt wait here consumes prefetch
    *(uint4*)(bdst + bswz(by0 + 16)) = breg1;
    __syncthreads();                            // drains A writes (kt=0) + B writes
    if (kt < 15) {                              // prefetch next tile AFTER barrier:
      breg0 = w2s4[(kt + 1) * 512 + tid * 2];   // rides under the MFMA phase
      breg1 = w2s4[(kt + 1) * 512 + tid * 2 + 1];
    }
    FragCvt af; af.u = *(const u16x8*)(Arow + ((kt * 64 + quad * 16) ^ arswz));
    const char* bsrc = (const char*)Bsh.B[kt & 1];
    #pragma unroll
    for (int nt = 0; nt < 8; ++nt) {
      const int bb2 = (nt * 16 + lidx) * 64 + quad * 16;
      FragCvt bf; bf.u = *(const u16x8*)(bsrc + bswz(bb2));
      acc[nt] = __builtin_amdgcn_mfma_f32_16x16x32_bf16(af.b, bf.b, acc[nt], 0, 0, 0);
    }
    // dbuf: kt+1's writes target the other slot, fenced by kt+1's barrier
  }

  // ---- epilogue: tanh + dot with V; lane covers rows wave*16+quad*4+r, cols nt*16+lidx ----
  float part[4] = {0.f, 0.f, 0.f, 0.f};
  #pragma unroll
  for (int nt = 0; nt < 8; ++nt) {
    const int col = nt * 16 + lidx;
    const float qv = qb[b * NU + col];
    const float vv = V[col];
    #pragma unroll
    for (int r = 0; r < 4; ++r)
      part[r] += fast_tanh(acc[nt][r] + qv) * vv;
  }
  #pragma unroll
  for (int m = 1; m <= 8; m <<= 1) {
    #pragma unroll
    for (int r = 0; r < 4; ++r) part[r] += __shfl_xor(part[r], m, 64);
  }
  // each wave now has COMPLETE scores for its 16 rows (summed over all 128 cols)
  if (lidx == 0) {
    #pragma unroll
    for (int r = 0; r < 4; ++r) Bsh.t.sw[wave * 16 + quad * 4 + r] = part[r];
  }
  __syncthreads();

  if (tid < 64) {
    float s = Bsh.t.sw[tid];
    float e = __expf(s + *bvp);                  // no max needed: |s| bounded by tanh*||V||
    wout[(size_t)b * NS + s0 + tid] = e;
    Bsh.t.e[tid] = e;
    float es = e;
    #pragma unroll
    for (int m = 1; m <= 32; m <<= 1) es += __shfl_xor(es, m, 64);
    if (tid == 0) atomicAdd(Lacc + b, es);
  }
  __syncthreads();

  // ---- weighted context from the A LDS tile (bf16, swizzled): zero extra global lines ----
  const int d0b = tid * 4;                       // byte offset of this thread's dword
  float c0 = 0.f, c1 = 0.f;
  #pragma unroll 8
  for (int r = 0; r < RR; ++r) {
    const float w = Bsh.t.e[r];
    const unsigned int pk = *(const unsigned int*)(Ab + aswz(r, d0b));
    c0 += w * bf2f(pk & 0xFFFFu);
    c1 += w * bf2f(pk >> 16);
  }
  const int d0 = tid * 2;
  atomicAdd(Cacc + b * ND + d0, c0);
  atomicAdd(Cacc + b * ND + d0 + 1, c1);
}

// ---------------- finalize: divide by denom ----------------
__global__ void finalize(const float* __restrict__ Cacc, const float* __restrict__ Lacc,
                         float* __restrict__ out) {
  int idx = blockIdx.x * 256 + threadIdx.x;   // 147456 total
  if (idx < NB * ND) {
    int b = idx >> 9;
    out[idx] = Cacc[idx] / Lacc[b];
  } else {
    int j = idx - NB * ND;
    int b = j >> 12;
    out[idx] = out[idx] / Lacc[b];
  }
}

extern "C" void kernel_launch(void* const* d_in, const int* in_sizes, int n_in,
                              void* d_out, int out_size, void* d_ws, size_t ws_size,
                              hipStream_t stream) {
  const float* query  = (const float*)d_in[0];
  const float* values = (const float*)d_in[1];
  const float* W1     = (const float*)d_in[2];
  const float* b1     = (const float*)d_in[3];
  const float* W2     = (const float*)d_in[4];
  const float* b2     = (const float*)d_in[5];
  const float* V      = (const float*)d_in[6];
  const float* bv     = (const float*)d_in[7];
  float* out = (float*)d_out;

  char* ws = (char*)d_ws;
  float* Cacc = (float*)ws;                               // 65536 B
  float* Lacc = (float*)(ws + 65536);                     // 128 B
  float* qb   = (float*)(ws + 66048);                     // 16384 B
  unsigned short* w2s = (unsigned short*)(ws + 66048 + 16384);  // 131072 B

  hipMemsetAsync(ws, 0, 66048 + 16384, stream);           // zero Cacc + Lacc + qb

  prep_qb <<<NB * 16, 256, 0, stream>>>(query, W1, b1, b2, qb);
  prep_w2s<<<256, 256, 0, stream>>>(W2, w2s);
  fused_attn<<<NB * (NS / RR), 256, 0, stream>>>(values, qb, w2s, V, bv,
                                                 out + NB * ND, Cacc, Lacc);
  finalize<<<(NB * ND + NB * NS) / 256, 256, 0, stream>>>(Cacc, Lacc, out);
}